// Round 13
// baseline (141.053 us; speedup 1.0000x reference)
//
#include <hip/hip_runtime.h>
#include <hip/hip_bf16.h>
#include <math.h>

#define L_SEQ 1024
#define BSZ 8
#define EMB 512
#define NH 8
#define DQ 64
#define BH 64          // BSZ*NH
#define NQKV 1536      // 3*NH*DQ

// Q is pre-scaled by (emb_dim/n_head)^-0.5 * log2(e) so that
// softmax numerator = exp2(mfma_score) with zero extra VALU per element.
#define SCALE_Q 0.18033688f

typedef __attribute__((ext_vector_type(8))) short short8;   // 8 bf16 = 4 VGPR
typedef __attribute__((ext_vector_type(4))) float f32x4;

#define GPTR(x) ((const __attribute__((address_space(1))) void*)(x))
#define LPTR(x) ((__attribute__((address_space(3))) void*)(x))

__device__ __forceinline__ unsigned short bf16u(float x) {
  __hip_bfloat16 h = __float2bfloat16(x);
  return *(unsigned short*)&h;
}

// ---------------------------------------------------------------------------
// Kernel 0: f32 -> bf16 convert of emb (8192x512) and W (1536x512).
// Block 0 additionally zero-inits Oacc/cnt for attn_fused.
// ---------------------------------------------------------------------------
__global__ __launch_bounds__(256) void to_bf16(
    const float* __restrict__ emb, const float* __restrict__ W,
    unsigned short* __restrict__ embB, unsigned short* __restrict__ WB,
    float* __restrict__ Oacc, int* __restrict__ cnt) {
  if (blockIdx.x == 0) {
    for (int i = threadIdx.x; i < BH * 64; i += 256) Oacc[i] = 0.f;
    if (threadIdx.x < BH) cnt[threadIdx.x] = 0;
  }
  const size_t t = (size_t)blockIdx.x * 256 + threadIdx.x;
  size_t base = t * 8;
  const float* src;
  unsigned short* dst;
  size_t off;
  if (base < (size_t)8192 * 512) { src = emb; dst = embB; off = base; }
  else { src = W; dst = WB; off = base - (size_t)8192 * 512; }
  float4 v0 = *(const float4*)&src[off];
  float4 v1 = *(const float4*)&src[off + 4];
  short8 o;
  o[0] = bf16u(v0.x); o[1] = bf16u(v0.y); o[2] = bf16u(v0.z); o[3] = bf16u(v0.w);
  o[4] = bf16u(v1.x); o[5] = bf16u(v1.y); o[6] = bf16u(v1.z); o[7] = bf16u(v1.w);
  *(short8*)&dst[off] = o;
}

// ---------------------------------------------------------------------------
// Kernel A: QKV projection, bf16 MFMA (m97 pattern). Q gets SCALE_Q folded in.
// Epilogue: C-tile staged to LDS (Cs[128][132] bf16), then each 64-col
// half-tile is a contiguous [bh][l][0..63] run -> short8 coalesced stores.
// ---------------------------------------------------------------------------
__global__ __launch_bounds__(256) void qkv_mfma(
    const unsigned short* __restrict__ A,   // embB [8192][512]
    const unsigned short* __restrict__ B,   // WB   [1536][512]
    const float* __restrict__ bias,
    unsigned short* __restrict__ Qb, unsigned short* __restrict__ Kb,
    unsigned short* __restrict__ Vb) {
  __shared__ __align__(16) unsigned short As[128][32];  // 8 KB, unpadded
  __shared__ __align__(16) unsigned short Bs[128][32];  // 8 KB
  __shared__ __align__(16) unsigned short Cs[128][132]; // 33 KB, +4 pad
  const int tid = threadIdx.x;
  const int wave = tid >> 6, lane = tid & 63;
  const int quad = lane >> 4, col = lane & 15;
  const int wr = wave >> 1, wc = wave & 1;
  const int m0 = blockIdx.y * 128, n0 = blockIdx.x * 128;
  const int r16 = lane >> 2, q4 = lane & 3;

  f32x4 acc[4][4] = {};

  for (int kt = 0; kt < EMB; kt += 32) {
    __syncthreads();
#pragma unroll
    for (int c = 0; c < 2; ++c) {
      const int rowA = (c * 4 + wave) * 16;
      __builtin_amdgcn_global_load_lds(
          GPTR(A + (size_t)(m0 + rowA + r16) * EMB + kt + q4 * 8),
          LPTR(&As[rowA][0]), 16, 0, 0);
      __builtin_amdgcn_global_load_lds(
          GPTR(B + (size_t)(n0 + rowA + r16) * EMB + kt + q4 * 8),
          LPTR(&Bs[rowA][0]), 16, 0, 0);
    }
    __syncthreads();
    short8 af[4], bf[4];
#pragma unroll
    for (int i = 0; i < 4; ++i)
      af[i] = *(const short8*)&As[wr * 64 + i * 16 + col][quad * 8];
#pragma unroll
    for (int j = 0; j < 4; ++j)
      bf[j] = *(const short8*)&Bs[wc * 64 + j * 16 + col][quad * 8];
#pragma unroll
    for (int i = 0; i < 4; ++i)
#pragma unroll
      for (int j = 0; j < 4; ++j)
        acc[i][j] =
            __builtin_amdgcn_mfma_f32_16x16x32_bf16(af[i], bf[j], acc[i][j],
                                                    0, 0, 0);
  }

#pragma unroll
  for (int j = 0; j < 4; ++j) {
    const int n = wc * 64 + j * 16 + col;     // tile col 0..127
    const float bj = bias[n0 + n];
    const bool isQ = (((n0 + n) >> 6) % 3) == 0;
#pragma unroll
    for (int i = 0; i < 4; ++i) {
      const int mrow = wr * 64 + i * 16 + quad * 4;
#pragma unroll
      for (int r = 0; r < 4; ++r) {
        float val = acc[i][j][r] + bj;
        if (isQ) val *= SCALE_Q;
        Cs[mrow + r][n] = bf16u(val);
      }
    }
  }
  __syncthreads();
  const int bb = lane >> 3, oct = lane & 7;
#pragma unroll
  for (int e = 0; e < 8; ++e) {
    const int idx = wave * 8 + e;
    const int half = idx >> 4, l = idx & 15;
    const int G = (n0 >> 6) + half;       // 64-col block id, 0..23
    const int h = G / 3, sel = G % 3;
    unsigned short* dst = (sel == 0) ? Qb : (sel == 1) ? Kb : Vb;
    short8 v = *(const short8*)&Cs[l * 8 + bb][half * 64 + oct * 8];
    const int lglob = (m0 >> 3) + l;
    *(short8*)&dst[(((size_t)(bb * NH + h)) * L_SEQ + lglob) * DQ + oct * 8] = v;
  }
}

// ---------------------------------------------------------------------------
// Kernel B (fused attention, v2): 256 thr, grid 512 = (bh=blk&63, qc=blk>>6).
// Block owns 128 q-rows; WAVE OWNS 32 ROWS (2 row-groups) so each K-fragment
// ds_read_b128 feeds TWO MFMAs -> per-CU LDS frag traffic halves vs R12
// (the R12 profile put LDS pipe ~23us at 49.6us kernel; this targets ~13).
// Same per-block K stream as R12 (R10 law: traffic ∝ blocks/bh).
// PASS 1 -> invz[2][4] in registers; PASS 2 -> cs[4][1024] colsums;
// V-combine (ushort2-vectorized); atomicAdd Oacc; 8th block does GroupNorm.
// Dbuf + post-barrier prefetch throughout.
// ---------------------------------------------------------------------------
__global__ __launch_bounds__(256) void attn_fused(
    const unsigned short* __restrict__ Qb, const unsigned short* __restrict__ Kb,
    const unsigned short* __restrict__ Vb,
    const float* __restrict__ gnw, const float* __restrict__ gnb,
    float* __restrict__ Oacc, int* __restrict__ cnt, float* __restrict__ out) {
  const int bh = blockIdx.x & 63;   // blk%8 = bh%8 -> same-bh blocks same XCD
  const int qc = blockIdx.x >> 6;   // 0..7, 128 q-rows each
  const int tid = threadIdx.x;
  const int wave = tid >> 6, lane = tid & 63;
  const int quad = lane >> 4, col = lane & 15;

  __shared__ __align__(16) unsigned short Ks[2][64][72];  // 18 KB
  __shared__ float cs[4][1024];                           // 16 KB
  __shared__ int lastFlag;

  const unsigned short* kbase = &Kb[(size_t)bh * L_SEQ * DQ];

  // Q fragments for this wave's 32 rows (2 row-groups, used in both passes)
  short8 qA[2][2];
#pragma unroll
  for (int rg = 0; rg < 2; ++rg) {
    const unsigned short* qp =
        &Qb[((size_t)bh * L_SEQ + qc * 128 + wave * 32 + rg * 16 + col) * DQ];
    qA[rg][0] = *(const short8*)&qp[quad * 8];
    qA[rg][1] = *(const short8*)&qp[32 + quad * 8];
  }

  const int sr = tid >> 2;         // staging row 0..63
  const int so = (tid & 3) * 16;   // staging col offset (shorts), 2x16B

  // ---------------- PASS 1: Z for own 32 rows ----------------
  float zacc[2][4] = {};
  short8 st0, st1;
  {
    const unsigned short* s8 = kbase + (size_t)sr * DQ + so;
    st0 = *(const short8*)s8;
    st1 = *(const short8*)(s8 + 8);
  }

#pragma unroll 2
  for (int kt = 0; kt < 16; ++kt) {
    const int buf = kt & 1;
    *(short8*)&Ks[buf][sr][so] = st0;
    *(short8*)&Ks[buf][sr][so + 8] = st1;
    __syncthreads();
    if (kt + 1 < 16) {  // post-barrier prefetch: in flight through compute
      const unsigned short* s8 =
          kbase + ((size_t)((kt + 1) * 64 + sr)) * DQ + so;
      st0 = *(const short8*)s8;
      st1 = *(const short8*)(s8 + 8);
    }
#pragma unroll
    for (int sub = 0; sub < 4; ++sub) {
      const unsigned short* kp = &Ks[buf][sub * 16 + col][0];
      short8 kb0 = *(const short8*)&kp[quad * 8];
      short8 kb1 = *(const short8*)&kp[32 + quad * 8];
#pragma unroll
      for (int rg = 0; rg < 2; ++rg) {
        f32x4 s = {0.f, 0.f, 0.f, 0.f};
        s = __builtin_amdgcn_mfma_f32_16x16x32_bf16(qA[rg][0], kb0, s, 0, 0, 0);
        s = __builtin_amdgcn_mfma_f32_16x16x32_bf16(qA[rg][1], kb1, s, 0, 0, 0);
#pragma unroll
        for (int j = 0; j < 4; ++j)
          zacc[rg][j] += __builtin_amdgcn_exp2f(s[j]);
      }
    }
  }
  float invz[2][4];
#pragma unroll
  for (int rg = 0; rg < 2; ++rg)
#pragma unroll
    for (int j = 0; j < 4; ++j) {
      float z = zacc[rg][j];
#pragma unroll
      for (int off = 1; off <= 8; off <<= 1) z += __shfl_xor(z, off, 64);
      invz[rg][j] = __builtin_amdgcn_rcpf(z);   // replicated across the quad
    }

  // ---------------- PASS 2: colsum contributions (K is L2-hot) ----------
  {
    const unsigned short* s8 = kbase + (size_t)sr * DQ + so;
    st0 = *(const short8*)s8;
    st1 = *(const short8*)(s8 + 8);
  }
#pragma unroll 2
  for (int kt = 0; kt < 16; ++kt) {
    const int buf = kt & 1;
    *(short8*)&Ks[buf][sr][so] = st0;
    *(short8*)&Ks[buf][sr][so + 8] = st1;
    __syncthreads();
    if (kt + 1 < 16) {
      const unsigned short* s8 =
          kbase + ((size_t)((kt + 1) * 64 + sr)) * DQ + so;
      st0 = *(const short8*)s8;
      st1 = *(const short8*)(s8 + 8);
    }
#pragma unroll
    for (int sub = 0; sub < 4; ++sub) {
      const unsigned short* kp = &Ks[buf][sub * 16 + col][0];
      short8 kb0 = *(const short8*)&kp[quad * 8];
      short8 kb1 = *(const short8*)&kp[32 + quad * 8];
      float partial = 0.f;
#pragma unroll
      for (int rg = 0; rg < 2; ++rg) {
        f32x4 s = {0.f, 0.f, 0.f, 0.f};
        s = __builtin_amdgcn_mfma_f32_16x16x32_bf16(qA[rg][0], kb0, s, 0, 0, 0);
        s = __builtin_amdgcn_mfma_f32_16x16x32_bf16(qA[rg][1], kb1, s, 0, 0, 0);
#pragma unroll
        for (int j = 0; j < 4; ++j)
          partial = fmaf(__builtin_amdgcn_exp2f(s[j]), invz[rg][j], partial);
      }
      // sum over the 4 quads (this wave's 32 rows); key = kt*64+sub*16+col
      partial += __shfl_xor(partial, 16, 64);
      partial += __shfl_xor(partial, 32, 64);
      if (quad == 0) cs[wave][kt * 64 + sub * 16 + col] = partial;
    }
  }
  __syncthreads();
  // reduce cs over the 4 waves -> cs[0][m]
  for (int m = tid; m < 1024; m += 256)
    cs[0][m] = cs[0][m] + cs[1][m] + cs[2][m] + cs[3][m];
  __syncthreads();

  // V-combine: partial O[d] = sum over ALL 1024 keys of cs[0][m]*V[m][d].
  // 8 groups x 128 keys; each thread handles 2 adjacent d (ushort2 loads).
  const int g8 = tid >> 5, d2 = (tid & 31) * 2;
  {
    const unsigned short* vb = &Vb[((size_t)bh * L_SEQ + g8 * 128) * DQ + d2];
    float o0 = 0.f, o1 = 0.f;
#pragma unroll 8
    for (int mm = 0; mm < 128; ++mm) {
      unsigned int pk = *(const unsigned int*)&vb[(size_t)mm * DQ];
      __hip_bfloat16 v0, v1;
      *(unsigned short*)&v0 = (unsigned short)(pk & 0xffff);
      *(unsigned short*)&v1 = (unsigned short)(pk >> 16);
      const float w = cs[0][g8 * 128 + mm];
      o0 = fmaf(w, __bfloat162float(v0), o0);
      o1 = fmaf(w, __bfloat162float(v1), o1);
    }
    cs[1][g8 * 64 + d2] = o0;     // cs[1] free after reduce
    cs[1][g8 * 64 + d2 + 1] = o1;
  }
  __syncthreads();
  if (tid < 64) {
    float p = 0.f;
#pragma unroll
    for (int g = 0; g < 8; ++g) p += cs[1][g * 64 + tid];
    atomicAdd(&Oacc[(size_t)bh * 64 + tid], p);
  }
  if (tid == 0) {
    __threadfence();                      // release: O adds visible first
    lastFlag = (atomicAdd(&cnt[bh], 1) == 7);
  }
  __syncthreads();
  if (lastFlag && tid < 64) {
    __threadfence();                      // acquire
    float v = atomicAdd(&Oacc[(size_t)bh * 64 + tid], 0.f);
    float s = v;
#pragma unroll
    for (int off = 32; off >= 1; off >>= 1) s += __shfl_xor(s, off, 64);
    float mean = s * (1.f / 64.f);
    float diff = v - mean;
    float sq = diff * diff;
#pragma unroll
    for (int off = 32; off >= 1; off >>= 1) sq += __shfl_xor(sq, off, 64);
    float var = sq * (1.f / 64.f);
    float o = diff * rsqrtf(var + 1e-5f);
    const int b = bh >> 3, h = bh & 7;
    out[(size_t)b * 512 + h * 64 + tid] = o * gnw[h] + gnb[h];
  }
}

extern "C" void kernel_launch(void* const* d_in, const int* in_sizes, int n_in,
                              void* d_out, int out_size, void* d_ws,
                              size_t ws_size, hipStream_t stream) {
  (void)in_sizes; (void)n_in; (void)out_size; (void)ws_size;
  const float* emb  = (const float*)d_in[0];
  const float* W    = (const float*)d_in[1];
  const float* bias = (const float*)d_in[2];
  const float* gnw  = (const float*)d_in[3];
  const float* gnb  = (const float*)d_in[4];
  float* out = (float*)d_out;

  char* ws = (char*)d_ws;
  const size_t perQ = (size_t)BH * L_SEQ * DQ;        // 4,194,304 elems
  unsigned short* embB = (unsigned short*)ws;                      // 8 MB
  unsigned short* WB   = (unsigned short*)(ws + 8u * 1024 * 1024); // 1.5 MB
  unsigned short* Qb   = (unsigned short*)(ws + 10u * 1024 * 1024);
  unsigned short* Kb   = Qb + perQ;   // @18M
  unsigned short* Vb   = Kb + perQ;   // @26M
  float* Oacc = (float*)(ws + 35u * 1024 * 1024);     // 16 KB
  int*   cnt  = (int*)(ws + 35u * 1024 * 1024 + 64u * 1024);

  to_bf16<<<dim3(2432), 256, 0, stream>>>(emb, W, embB, WB, Oacc, cnt);
  qkv_mfma<<<dim3(NQKV / 128, 8192 / 128), 256, 0, stream>>>(
      embB, WB, bias, Qb, Kb, Vb);
  attn_fused<<<dim3(512), 256, 0, stream>>>(Qb, Kb, Vb, gnw, gnb,
                                            Oacc, cnt, out);
}